// Round 1
// baseline (628.488 us; speedup 1.0000x reference)
//
#include <hip/hip_runtime.h>
#include <math.h>

#define D 128
#define NS 2048          // b*n = 2*1024
#define NCHUNK 16        // chunks per (b,layer) over n=1024
#define CLEN 64          // chunk length

__device__ __forceinline__ float sigmoidf_(float x) {
    return 1.0f / (1.0f + expf(-x));
}

// Coalesced column-major matvec: out[tid] = sum_r x[r] * M[r*D + tid]
// 4 accumulators to break the FMA dependency chain.
__device__ __forceinline__ float matvec_col(const float* __restrict__ M,
                                            const float* x, int tid)
{
    float a0 = 0.f, a1 = 0.f, a2 = 0.f, a3 = 0.f;
#pragma unroll 4
    for (int r = 0; r < D; r += 4) {
        a0 += x[r]     * M[(r)     * D + tid];
        a1 += x[r + 1] * M[(r + 1) * D + tid];
        a2 += x[r + 2] * M[(r + 2) * D + tid];
        a3 += x[r + 3] * M[(r + 3) * D + tid];
    }
    return (a0 + a1) + (a2 + a3);
}

// ---------------- Phase 0: transpose W so backward reads are coalesced ----
// WT[l][c][r] = W[l][r][c].  grid = 4 layers x 16 (32x32) tiles.
__global__ __launch_bounds__(256) void transposeW(
    const float* __restrict__ W, float* __restrict__ WT)
{
    const int l   = blockIdx.x >> 4;
    const int tl  = blockIdx.x & 15;
    const int tr  = tl >> 2, tc = tl & 3;
    const int tid = threadIdx.x;
    const int lr  = tid >> 5;      // 0..7
    const int lc  = tid & 31;
    __shared__ float tile[32][33];
#pragma unroll
    for (int k = 0; k < 4; ++k)
        tile[lr + 8 * k][lc] =
            W[l * 16384 + (tr * 32 + lr + 8 * k) * 128 + tc * 32 + lc];
    __syncthreads();
#pragma unroll
    for (int k = 0; k < 4; ++k)
        WT[l * 16384 + (tc * 32 + lr + 8 * k) * 128 + tr * 32 + lc] =
            tile[lc][lr + 8 * k];
}

// ---------------- Phase 1: per-sample forward/backward, rank-1 factors ----
// block = one sample, 128 threads
__global__ __launch_bounds__(128) void phase1(
    const float* __restrict__ seq, const float* __restrict__ W,
    const float* __restrict__ WT, const float* __restrict__ Wkv,
    const float* __restrict__ w_lr,
    float* __restrict__ ws_u, float* __restrict__ ws_g,
    float* __restrict__ lossbuf)
{
    const int s   = blockIdx.x;    // 0..2047
    const int tid = threadIdx.x;   // 0..127

    __shared__ float sseq[D], xbuf[D], vbuf[D], gbuf[D];
    __shared__ float red2[2];

    const float sv = seq[s * D + tid];
    sseq[tid] = sv;

    // scale = -(seq_row . w_lr) via wave shuffle reduce
    float p = sv * w_lr[tid];
#pragma unroll
    for (int off = 32; off > 0; off >>= 1) p += __shfl_down(p, off, 64);
    if ((tid & 63) == 0) red2[tid >> 6] = p;
    __syncthreads();                       // covers sseq + red2
    const float scale = -(red2[0] + red2[1]);

    // k, v = seq_row @ Wkv   (coalesced; 2-way split accumulators)
    {
        float k0 = 0.f, k1 = 0.f, v0 = 0.f, v1 = 0.f;
#pragma unroll 4
        for (int r = 0; r < D; r += 2) {
            float x0 = sseq[r], x1 = sseq[r + 1];
            k0 += x0 * Wkv[r * 256 + tid];
            v0 += x0 * Wkv[r * 256 + 128 + tid];
            k1 += x1 * Wkv[(r + 1) * 256 + tid];
            v1 += x1 * Wkv[(r + 1) * 256 + 128 + tid];
        }
        float kacc = k0 + k1, vacc = v0 + v1;
        xbuf[tid] = kacc;
        vbuf[tid] = vacc;
        ws_u[(s * 4 + 0) * D + tid] = kacc;   // u0 = k
    }
    __syncthreads();

    // forward: h kept in registers (only ever read by the same thread)
    float h0r, h1r, h2r;
    // layer 0
    {
        float h = matvec_col(W + 0 * 16384, xbuf, tid);
        h0r = h;
        float a = h * sigmoidf_(h);
        __syncthreads();
        xbuf[tid] = a;
        ws_u[(s * 4 + 1) * D + tid] = a;
        __syncthreads();
    }
    // layer 1
    {
        float h = matvec_col(W + 1 * 16384, xbuf, tid);
        h1r = h;
        float a = h * sigmoidf_(h);
        __syncthreads();
        xbuf[tid] = a;
        ws_u[(s * 4 + 2) * D + tid] = a;
        __syncthreads();
    }
    // layer 2
    {
        float h = matvec_col(W + 2 * 16384, xbuf, tid);
        h2r = h;
        float a = h * sigmoidf_(h);
        __syncthreads();
        xbuf[tid] = a;
        ws_u[(s * 4 + 3) * D + tid] = a;
        __syncthreads();
    }
    // layer 3 (no activation) -> pred
    const float hfin = matvec_col(W + 3 * 16384, xbuf, tid);
    const float diff = hfin - vbuf[tid];

    // loss via wave shuffle reduce
    {
        float lp = diff * diff;
#pragma unroll
        for (int off = 32; off > 0; off >>= 1) lp += __shfl_down(lp, off, 64);
        if ((tid & 63) == 0) red2[tid >> 6] = lp;
        __syncthreads();
        if (tid == 0) lossbuf[s] = (red2[0] + red2[1]) * (1.0f / 128.0f);
    }

    // backward
    float g = diff * (2.0f / 128.0f);           // g3
    gbuf[tid] = g;
    ws_g[(s * 4 + 3) * D + tid] = scale * g;
    __syncthreads();

    // da2 = W3[tid,:] . g3 = WT3[:,tid] . g3  (coalesced) ; g2 via h2
    {
        float da = matvec_col(WT + 3 * 16384, gbuf, tid);
        float sg = sigmoidf_(h2r);
        g = da * (sg * (1.0f + h2r * (1.0f - sg)));
    }
    __syncthreads();
    gbuf[tid] = g;
    ws_g[(s * 4 + 2) * D + tid] = scale * g;
    __syncthreads();

    // da1 with WT2 ; g1 via h1
    {
        float da = matvec_col(WT + 2 * 16384, gbuf, tid);
        float sg = sigmoidf_(h1r);
        g = da * (sg * (1.0f + h1r * (1.0f - sg)));
    }
    __syncthreads();
    gbuf[tid] = g;
    ws_g[(s * 4 + 1) * D + tid] = scale * g;
    __syncthreads();

    // da0 with WT1 ; g0 via h0
    {
        float da = matvec_col(WT + 1 * 16384, gbuf, tid);
        float sg = sigmoidf_(h0r);
        g = da * (sg * (1.0f + h0r * (1.0f - sg)));
    }
    ws_g[(s * 4 + 0) * D + tid] = scale * g;
}

// ---------------- Phase A: chunk sums (sum of 64 rank-1 products) ---------
// block = (b, layer, chunk, row-half); 256 blocks, 256 threads, 32 acc each.
// Double-buffered LDS + register prefetch: one barrier per timestep.
__global__ __launch_bounds__(256) void phaseA(
    const float* __restrict__ ws_u, const float* __restrict__ ws_g,
    float* __restrict__ chunkS)
{
    const int bx    = blockIdx.x;       // 0..255
    const int half  = bx & 1;
    const int cs    = bx >> 1;          // 0..127
    const int j     = cs & 15;
    const int layer = (cs >> 4) & 3;
    const int b     = cs >> 6;
    const int tid   = threadIdx.x;
    const int hi    = tid >> 7;         // 0/1
    const int c     = tid & 127;

    __shared__ float us[2][64], gs[2][D];
    float acc[32];
#pragma unroll
    for (int k = 0; k < 32; ++k) acc[k] = 0.f;

    const int samp0 = b * 1024 + j * CLEN;
    float ru = 0.f, rg = 0.f;
    if (tid < 128) rg = ws_g[(samp0 * 4 + layer) * D + tid];
    if (tid < 64)  ru = ws_u[(samp0 * 4 + layer) * D + half * 64 + tid];

    for (int t = 0; t < CLEN; ++t) {
        const int pb = t & 1;
        if (tid < 128) gs[pb][tid] = rg;
        if (tid < 64)  us[pb][tid] = ru;
        if (t + 1 < CLEN) {
            const int samp = samp0 + t + 1;
            if (tid < 128) rg = ws_g[(samp * 4 + layer) * D + tid];
            if (tid < 64)  ru = ws_u[(samp * 4 + layer) * D + half * 64 + tid];
        }
        __syncthreads();
        const float gv = gs[pb][c];
#pragma unroll
        for (int k = 0; k < 32; ++k) acc[k] += us[pb][2 * k + hi] * gv;
    }
    float* out = chunkS + (size_t)cs * 16384 + half * 8192;
#pragma unroll
    for (int k = 0; k < 32; ++k) out[k * 256 + tid] = acc[k];
}

// ---------------- Phase A2: exclusive scan of chunk sums (in place) -------
__global__ __launch_bounds__(256) void phaseA2(float* __restrict__ chunkS)
{
    const int g  = blockIdx.x * 256 + threadIdx.x;  // 0..131071
    const int bl = g >> 14;                         // (b,layer) 0..7
    const int e  = g & 16383;
    float* base = chunkS + (size_t)bl * NCHUNK * 16384 + e;
    float run = 0.f;
    for (int j = 0; j < NCHUNK; ++j) {
        float t = base[(size_t)j * 16384];
        base[(size_t)j * 16384] = run;
        run += t;
    }
}

// ---------------- Phase B: carry + rank-1 scan, stream grads --------------
// block = (b, layer, chunk, rowtile/4); 256 threads; tile 32 rows x 128 cols.
// No LDS, no barriers: per-thread float4 loads + register prefetch.
__global__ __launch_bounds__(256) void phaseB(
    const float* __restrict__ ws_u, const float* __restrict__ ws_g,
    const float* __restrict__ chunkS, const float* __restrict__ W,
    float* __restrict__ out_grads, float* __restrict__ out_next)
{
    const int id    = blockIdx.x;         // 0..511
    const int rt    = id & 3;
    const int j     = (id >> 2) & 15;
    const int layer = (id >> 6) & 3;
    const int b     = id >> 8;
    const int cs    = (b * 4 + layer) * NCHUNK + j;
    const int tid   = threadIdx.x;

    const int c4 = (tid & 31) * 4;        // column (x4)
    const int rq = tid >> 5;              // 0..7
    const int r0 = rt * 32 + rq * 4;      // 4 consecutive rows

    float4 acc[4];
    const float* carry = chunkS + (size_t)cs * 16384;
#pragma unroll
    for (int k = 0; k < 4; ++k)
        acc[k] = *(const float4*)(carry + (r0 + k) * 128 + c4);

    const int samp0 = b * 1024 + j * CLEN;
    const float* gbase = ws_g + ((size_t)samp0 * 4 + layer) * D;
    const float* ubase = ws_u + ((size_t)samp0 * 4 + layer) * D;
    // stride between consecutive timesteps in ws_*: 4*D = 512 floats

    float4 gv = *(const float4*)(gbase + c4);
    float4 u4 = *(const float4*)(ubase + r0);

    for (int t = 0; t < CLEN; ++t) {
        float4 gn = gv, un = u4;
        if (t + 1 < CLEN) {
            gn = *(const float4*)(gbase + (t + 1) * 512 + c4);
            un = *(const float4*)(ubase + (t + 1) * 512 + r0);
        }
        float* obase = out_grads + ((size_t)(samp0 + t) * 4 + layer) * 16384;

        acc[0].x += u4.x * gv.x; acc[0].y += u4.x * gv.y;
        acc[0].z += u4.x * gv.z; acc[0].w += u4.x * gv.w;
        acc[1].x += u4.y * gv.x; acc[1].y += u4.y * gv.y;
        acc[1].z += u4.y * gv.z; acc[1].w += u4.y * gv.w;
        acc[2].x += u4.z * gv.x; acc[2].y += u4.z * gv.y;
        acc[2].z += u4.z * gv.z; acc[2].w += u4.z * gv.w;
        acc[3].x += u4.w * gv.x; acc[3].y += u4.w * gv.y;
        acc[3].z += u4.w * gv.z; acc[3].w += u4.w * gv.w;

        *(float4*)(obase + (r0 + 0) * 128 + c4) = acc[0];
        *(float4*)(obase + (r0 + 1) * 128 + c4) = acc[1];
        *(float4*)(obase + (r0 + 2) * 128 + c4) = acc[2];
        *(float4*)(obase + (r0 + 3) * 128 + c4) = acc[3];

        gv = gn; u4 = un;
    }

    if (j == NCHUNK - 1) {
#pragma unroll
        for (int k = 0; k < 4; ++k) {
            const int r = r0 + k;
            float4 w4 = *(const float4*)(W + layer * 16384 + r * 128 + c4);
            float4 o;
            o.x = acc[k].x + w4.x;
            o.y = acc[k].y + w4.y;
            o.z = acc[k].z + w4.z;
            o.w = acc[k].w + w4.w;
            *(float4*)(out_next + ((size_t)(b * 4 + layer)) * 16384 + r * 128 + c4) = o;
        }
    }
}

// ---------------- Loss reduction -----------------------------------------
__global__ __launch_bounds__(256) void lossk(const float* __restrict__ lossbuf,
                                             float* __restrict__ out)
{
    __shared__ float red[256];
    const int tid = threadIdx.x;
    float s = 0.f;
    for (int i = tid; i < NS; i += 256) s += lossbuf[i];
    red[tid] = s;
    __syncthreads();
    for (int off = 128; off > 0; off >>= 1) {
        if (tid < off) red[tid] += red[tid + off];
        __syncthreads();
    }
    if (tid == 0) out[0] = red[0] * (1.0f / (float)NS);
}

extern "C" void kernel_launch(void* const* d_in, const int* in_sizes, int n_in,
                              void* d_out, int out_size, void* d_ws, size_t ws_size,
                              hipStream_t stream)
{
    const float* seq   = (const float*)d_in[0];
    const float* W     = (const float*)d_in[1];
    const float* Wkv   = (const float*)d_in[2];
    const float* w_lr  = (const float*)d_in[3];
    // w_mom (d_in[4]) and w_decay (d_in[5]) do not affect any output.

    float* out = (float*)d_out;
    float* ws  = (float*)d_ws;

    float* ws_u    = ws;                         // 1048576 floats
    float* ws_g    = ws + 1048576;               // 1048576 floats
    float* chunkS  = ws + 2097152;               // 2097152 floats
    float* lossbuf = ws + 4194304;               // 2048 floats
    // WT aliases chunkS: WT is only read during phase1; chunkS is first
    // written by phaseA, which runs strictly after phase1 on the stream.
    float* WT      = chunkS;                     // 65536 floats (4 layers)

    float* out_grads = out;                      // 134217728 floats
    float* out_next  = out + 134217728;          // 131072 floats
    float* out_loss  = out + 134348800;          // 1 float

    transposeW<<<64, 256, 0, stream>>>(W, WT);
    phase1<<<NS, 128, 0, stream>>>(seq, W, WT, Wkv, w_lr, ws_u, ws_g, lossbuf);
    phaseA<<<256, 256, 0, stream>>>(ws_u, ws_g, chunkS);
    phaseA2<<<512, 256, 0, stream>>>(chunkS);
    phaseB<<<512, 256, 0, stream>>>(ws_u, ws_g, chunkS, W, out_grads, out_next);
    lossk<<<1, 256, 0, stream>>>(lossbuf, out_loss);
}

// Round 4
// 624.810 us; speedup vs baseline: 1.0059x; 1.0059x over previous
//
#include <hip/hip_runtime.h>
#include <math.h>

#define D 128
#define NS 2048          // b*n = 2*1024

typedef float v4f __attribute__((ext_vector_type(4)));

__device__ __forceinline__ float sigmoidf_(float x) {
    return 1.0f / (1.0f + expf(-x));
}

// acc[s] = sum_r xsg[s][r] * M[r*D + lt]   (4 samples share each W load)
__device__ __forceinline__ void matvec4(const float* __restrict__ M,
                                        const float (*xsg)[D], int lt,
                                        float acc[4])
{
    acc[0] = 0.f; acc[1] = 0.f; acc[2] = 0.f; acc[3] = 0.f;
#pragma unroll 2
    for (int r = 0; r < D; r += 4) {
        v4f x0 = *(const v4f*)&xsg[0][r];
        v4f x1 = *(const v4f*)&xsg[1][r];
        v4f x2 = *(const v4f*)&xsg[2][r];
        v4f x3 = *(const v4f*)&xsg[3][r];
#pragma unroll
        for (int rr = 0; rr < 4; ++rr) {
            float w = M[(r + rr) * D + lt];
            acc[0] += x0[rr] * w;
            acc[1] += x1[rr] * w;
            acc[2] += x2[rr] * w;
            acc[3] += x3[rr] * w;
        }
    }
}

// ---------------- Phase 0: transpose W so backward reads are coalesced ----
__global__ __launch_bounds__(256) void transposeW(
    const float* __restrict__ W, float* __restrict__ WT)
{
    const int l   = blockIdx.x >> 4;
    const int tl  = blockIdx.x & 15;
    const int tr  = tl >> 2, tc = tl & 3;
    const int tid = threadIdx.x;
    const int lr  = tid >> 5;      // 0..7
    const int lc  = tid & 31;
    __shared__ float tile[32][33];
#pragma unroll
    for (int k = 0; k < 4; ++k)
        tile[lr + 8 * k][lc] =
            W[l * 16384 + (tr * 32 + lr + 8 * k) * 128 + tc * 32 + lc];
    __syncthreads();
#pragma unroll
    for (int k = 0; k < 4; ++k)
        WT[l * 16384 + (tc * 32 + lr + 8 * k) * 128 + tr * 32 + lc] =
            tile[lc][lr + 8 * k];
}

// ---------------- Phase 1: forward/backward, 8 samples per block ----------
// 256 threads = 2 groups x 128; each group processes 4 samples sharing W loads.
__global__ __launch_bounds__(256) void phase1(
    const float* __restrict__ seq, const float* __restrict__ W,
    const float* __restrict__ WT, const float* __restrict__ Wkv,
    const float* __restrict__ w_lr,
    float* __restrict__ ws_u, float* __restrict__ ws_g,
    float* __restrict__ lossbuf)
{
    const int tid = threadIdx.x;
    const int g   = tid >> 7;        // sample-group 0/1
    const int lt  = tid & 127;       // lane within group = output dim
    const int wv  = lt >> 6;         // wave-half within group
    const int sbase = blockIdx.x * 8 + g * 4;

    __shared__ float sseq[2][4][D];
    __shared__ float xs[2][4][D];    // activations / gradient broadcast
    __shared__ float red[2][4][2];

#pragma unroll
    for (int s = 0; s < 4; ++s)
        sseq[g][s][lt] = seq[(sbase + s) * D + lt];

    const float wlr = w_lr[lt];
#pragma unroll
    for (int s = 0; s < 4; ++s) {
        float p = sseq[g][s][lt] * wlr;
#pragma unroll
        for (int off = 32; off > 0; off >>= 1) p += __shfl_down(p, off, 64);
        if ((tid & 63) == 0) red[g][s][wv] = p;
    }
    __syncthreads();
    float sc[4];
#pragma unroll
    for (int s = 0; s < 4; ++s) sc[s] = -(red[g][s][0] + red[g][s][1]);

    // kv = seq @ Wkv (k and v columns; W elements shared across 4 samples)
    float ka[4] = {0.f, 0.f, 0.f, 0.f}, va[4] = {0.f, 0.f, 0.f, 0.f};
#pragma unroll 2
    for (int r = 0; r < D; r += 4) {
        v4f x0 = *(const v4f*)&sseq[g][0][r];
        v4f x1 = *(const v4f*)&sseq[g][1][r];
        v4f x2 = *(const v4f*)&sseq[g][2][r];
        v4f x3 = *(const v4f*)&sseq[g][3][r];
#pragma unroll
        for (int rr = 0; rr < 4; ++rr) {
            float wk  = Wkv[(r + rr) * 256 + lt];
            float wv2 = Wkv[(r + rr) * 256 + 128 + lt];
            ka[0] += x0[rr] * wk;  va[0] += x0[rr] * wv2;
            ka[1] += x1[rr] * wk;  va[1] += x1[rr] * wv2;
            ka[2] += x2[rr] * wk;  va[2] += x2[rr] * wv2;
            ka[3] += x3[rr] * wk;  va[3] += x3[rr] * wv2;
        }
    }
    float vr[4];
#pragma unroll
    for (int s = 0; s < 4; ++s) {
        vr[s] = va[s];
        xs[g][s][lt] = ka[s];
        ws_u[((size_t)(sbase + s) * 4 + 0) * D + lt] = ka[s];
    }
    __syncthreads();

    float h0r[4], h1r[4], h2r[4], acc[4];

    // layer 0
    matvec4(W + 0 * 16384, xs[g], lt, acc);
    __syncthreads();
#pragma unroll
    for (int s = 0; s < 4; ++s) {
        h0r[s] = acc[s];
        float a = acc[s] * sigmoidf_(acc[s]);
        xs[g][s][lt] = a;
        ws_u[((size_t)(sbase + s) * 4 + 1) * D + lt] = a;
    }
    __syncthreads();

    // layer 1
    matvec4(W + 1 * 16384, xs[g], lt, acc);
    __syncthreads();
#pragma unroll
    for (int s = 0; s < 4; ++s) {
        h1r[s] = acc[s];
        float a = acc[s] * sigmoidf_(acc[s]);
        xs[g][s][lt] = a;
        ws_u[((size_t)(sbase + s) * 4 + 2) * D + lt] = a;
    }
    __syncthreads();

    // layer 2
    matvec4(W + 2 * 16384, xs[g], lt, acc);
    __syncthreads();
#pragma unroll
    for (int s = 0; s < 4; ++s) {
        h2r[s] = acc[s];
        float a = acc[s] * sigmoidf_(acc[s]);
        xs[g][s][lt] = a;
        ws_u[((size_t)(sbase + s) * 4 + 3) * D + lt] = a;
    }
    __syncthreads();

    // layer 3 (no activation) -> pred
    matvec4(W + 3 * 16384, xs[g], lt, acc);
    float diff[4];
#pragma unroll
    for (int s = 0; s < 4; ++s) diff[s] = acc[s] - vr[s];

    // loss
#pragma unroll
    for (int s = 0; s < 4; ++s) {
        float lp = diff[s] * diff[s];
#pragma unroll
        for (int off = 32; off > 0; off >>= 1) lp += __shfl_down(lp, off, 64);
        if ((tid & 63) == 0) red[g][s][wv] = lp;
    }
    __syncthreads();       // red visible; layer-3 xs reads complete
    if (lt == 0) {
#pragma unroll
        for (int s = 0; s < 4; ++s)
            lossbuf[sbase + s] = (red[g][s][0] + red[g][s][1]) * (1.0f / 128.0f);
    }

    // backward
    float gcur[4];
#pragma unroll
    for (int s = 0; s < 4; ++s) {
        gcur[s] = diff[s] * (2.0f / 128.0f);
        xs[g][s][lt] = gcur[s];
        ws_g[((size_t)(sbase + s) * 4 + 3) * D + lt] = sc[s] * gcur[s];
    }
    __syncthreads();

    // da2 via WT3 ; g2 via h2
    matvec4(WT + 3 * 16384, xs[g], lt, acc);
    __syncthreads();       // xs reads complete before overwrite
#pragma unroll
    for (int s = 0; s < 4; ++s) {
        float hv = h2r[s], sg = sigmoidf_(hv);
        gcur[s] = acc[s] * (sg * (1.0f + hv * (1.0f - sg)));
        xs[g][s][lt] = gcur[s];
        ws_g[((size_t)(sbase + s) * 4 + 2) * D + lt] = sc[s] * gcur[s];
    }
    __syncthreads();

    // da1 via WT2 ; g1 via h1
    matvec4(WT + 2 * 16384, xs[g], lt, acc);
    __syncthreads();
#pragma unroll
    for (int s = 0; s < 4; ++s) {
        float hv = h1r[s], sg = sigmoidf_(hv);
        gcur[s] = acc[s] * (sg * (1.0f + hv * (1.0f - sg)));
        xs[g][s][lt] = gcur[s];
        ws_g[((size_t)(sbase + s) * 4 + 1) * D + lt] = sc[s] * gcur[s];
    }
    __syncthreads();

    // da0 via WT1 ; g0 via h0
    matvec4(WT + 1 * 16384, xs[g], lt, acc);
#pragma unroll
    for (int s = 0; s < 4; ++s) {
        float hv = h0r[s], sg = sigmoidf_(hv);
        gcur[s] = acc[s] * (sg * (1.0f + hv * (1.0f - sg)));
        ws_g[((size_t)(sbase + s) * 4 + 0) * D + lt] = sc[s] * gcur[s];
    }
}

// ---------------- Phase A: chunk sums (sum of CL rank-1 products) ---------
// block = (b, layer, chunk, row-half); 16*NCH blocks, 256 threads, 32 acc each.
template<int NCH, int CL>
__global__ __launch_bounds__(256) void phaseA(
    const float* __restrict__ ws_u, const float* __restrict__ ws_g,
    float* __restrict__ chunkS)
{
    const int bx    = blockIdx.x;
    const int half  = bx & 1;
    const int cs    = bx >> 1;            // 0..8*NCH-1
    const int j     = cs & (NCH - 1);
    const int layer = (cs / NCH) & 3;
    const int b     = cs / (NCH * 4);
    const int tid   = threadIdx.x;
    const int hi    = tid >> 7;           // 0/1
    const int c     = tid & 127;

    __shared__ float us[2][64], gs[2][D];
    float acc[32];
#pragma unroll
    for (int k = 0; k < 32; ++k) acc[k] = 0.f;

    const int samp0 = b * 1024 + j * CL;
    float ru = 0.f, rg = 0.f;
    if (tid < 128) rg = ws_g[(samp0 * 4 + layer) * D + tid];
    if (tid < 64)  ru = ws_u[(samp0 * 4 + layer) * D + half * 64 + tid];

    for (int t = 0; t < CL; ++t) {
        const int pb = t & 1;
        if (tid < 128) gs[pb][tid] = rg;
        if (tid < 64)  us[pb][tid] = ru;
        if (t + 1 < CL) {
            const int samp = samp0 + t + 1;
            if (tid < 128) rg = ws_g[(samp * 4 + layer) * D + tid];
            if (tid < 64)  ru = ws_u[(samp * 4 + layer) * D + half * 64 + tid];
        }
        __syncthreads();
        const float gv = gs[pb][c];
#pragma unroll
        for (int k = 0; k < 32; ++k) acc[k] += us[pb][2 * k + hi] * gv;
    }
    float* out = chunkS + (size_t)cs * 16384 + half * 8192;
#pragma unroll
    for (int k = 0; k < 32; ++k) out[k * 256 + tid] = acc[k];
}

// ---------------- Phase A2: exclusive scan of chunk sums (in place) -------
template<int NCH>
__global__ __launch_bounds__(256) void phaseA2(float* __restrict__ chunkS)
{
    const int g  = blockIdx.x * 256 + threadIdx.x;  // 0..131071
    const int bl = g >> 14;                         // (b,layer) 0..7
    const int e  = g & 16383;
    float* base = chunkS + (size_t)bl * NCH * 16384 + e;
    float run = 0.f;
    for (int j = 0; j < NCH; ++j) {
        float t = base[(size_t)j * 16384];
        base[(size_t)j * 16384] = run;
        run += t;
    }
}

// ---------------- Phase B: carry + rank-1 scan, stream grads --------------
// 32*NCH blocks; 256 threads; tile 32 rows x 128 cols; NT stores.
template<int NCH, int CL>
__global__ __launch_bounds__(256) void phaseB(
    const float* __restrict__ ws_u, const float* __restrict__ ws_g,
    const float* __restrict__ chunkS, const float* __restrict__ W,
    float* __restrict__ out_grads, float* __restrict__ out_next)
{
    const int id    = blockIdx.x;
    const int rt    = id & 3;
    const int rest  = id >> 2;
    const int j     = rest & (NCH - 1);
    const int rest2 = rest / NCH;
    const int layer = rest2 & 3;
    const int b     = rest2 >> 2;
    const int cs    = (b * 4 + layer) * NCH + j;
    const int tid   = threadIdx.x;

    const int c4 = (tid & 31) * 4;        // column (x4)
    const int rq = tid >> 5;              // 0..7
    const int r0 = rt * 32 + rq * 4;      // 4 consecutive rows

    v4f acc[4];
    const float* carry = chunkS + (size_t)cs * 16384;
#pragma unroll
    for (int k = 0; k < 4; ++k)
        acc[k] = *(const v4f*)(carry + (r0 + k) * 128 + c4);

    const int samp0 = b * 1024 + j * CL;
    const float* gbase = ws_g + ((size_t)samp0 * 4 + layer) * D;
    const float* ubase = ws_u + ((size_t)samp0 * 4 + layer) * D;

    v4f gv = *(const v4f*)(gbase + c4);
    v4f u4 = *(const v4f*)(ubase + r0);

    for (int t = 0; t < CL; ++t) {
        v4f gn = gv, un = u4;
        if (t + 1 < CL) {
            gn = *(const v4f*)(gbase + (t + 1) * 512 + c4);
            un = *(const v4f*)(ubase + (t + 1) * 512 + r0);
        }
        float* obase = out_grads + ((size_t)(samp0 + t) * 4 + layer) * 16384;

        acc[0] += u4[0] * gv;
        acc[1] += u4[1] * gv;
        acc[2] += u4[2] * gv;
        acc[3] += u4[3] * gv;

        __builtin_nontemporal_store(acc[0], (v4f*)(obase + (r0 + 0) * 128 + c4));
        __builtin_nontemporal_store(acc[1], (v4f*)(obase + (r0 + 1) * 128 + c4));
        __builtin_nontemporal_store(acc[2], (v4f*)(obase + (r0 + 2) * 128 + c4));
        __builtin_nontemporal_store(acc[3], (v4f*)(obase + (r0 + 3) * 128 + c4));

        gv = gn; u4 = un;
    }

    if (j == NCH - 1) {
#pragma unroll
        for (int k = 0; k < 4; ++k) {
            const int r = r0 + k;
            v4f w4 = *(const v4f*)(W + layer * 16384 + r * 128 + c4);
            v4f o = acc[k] + w4;
            *(v4f*)(out_next + ((size_t)(b * 4 + layer)) * 16384 + r * 128 + c4) = o;
        }
    }
}

// ---------------- Loss reduction -----------------------------------------
__global__ __launch_bounds__(256) void lossk(const float* __restrict__ lossbuf,
                                             float* __restrict__ out)
{
    __shared__ float red[256];
    const int tid = threadIdx.x;
    float s = 0.f;
    for (int i = tid; i < NS; i += 256) s += lossbuf[i];
    red[tid] = s;
    __syncthreads();
    for (int off = 128; off > 0; off >>= 1) {
        if (tid < off) red[tid] += red[tid + off];
        __syncthreads();
    }
    if (tid == 0) out[0] = red[0] * (1.0f / (float)NS);
}

extern "C" void kernel_launch(void* const* d_in, const int* in_sizes, int n_in,
                              void* d_out, int out_size, void* d_ws, size_t ws_size,
                              hipStream_t stream)
{
    const float* seq   = (const float*)d_in[0];
    const float* W     = (const float*)d_in[1];
    const float* Wkv   = (const float*)d_in[2];
    const float* w_lr  = (const float*)d_in[3];
    // w_mom (d_in[4]) and w_decay (d_in[5]) do not affect any output.

    float* out = (float*)d_out;
    float* ws  = (float*)d_ws;

    // NCHUNK=32 needs 2097152 + 8*32*16384 + 2048 floats = ~25.2 MB of ws.
    // Fall back to NCHUNK=16 (~16.8 MB, the previously-verified footprint)
    // if the workspace is smaller.
    const size_t need32 = ((size_t)2097152 + (size_t)8 * 32 * 16384 + 2048) * 4;
    const bool big = ws_size >= need32;
    const size_t chunkFloats = (size_t)8 * (big ? 32 : 16) * 16384;

    float* ws_u    = ws;                          // 1048576 floats
    float* ws_g    = ws + 1048576;                // 1048576 floats
    float* chunkS  = ws + 2097152;                // chunkFloats floats
    float* lossbuf = ws + 2097152 + chunkFloats;  // 2048 floats
    // WT aliases chunkS: WT is only read during phase1; chunkS is first
    // written by phaseA, which runs strictly after phase1 on the stream.
    float* WT      = chunkS;                      // 65536 floats (4 layers)

    float* out_grads = out;                       // 134217728 floats
    float* out_next  = out + 134217728;           // 131072 floats
    float* out_loss  = out + 134348800;           // 1 float

    transposeW<<<64, 256, 0, stream>>>(W, WT);
    phase1<<<NS / 8, 256, 0, stream>>>(seq, W, WT, Wkv, w_lr, ws_u, ws_g, lossbuf);
    if (big) {
        phaseA<32, 32><<<512, 256, 0, stream>>>(ws_u, ws_g, chunkS);
        phaseA2<32><<<512, 256, 0, stream>>>(chunkS);
        phaseB<32, 32><<<1024, 256, 0, stream>>>(ws_u, ws_g, chunkS, W,
                                                 out_grads, out_next);
    } else {
        phaseA<16, 64><<<256, 256, 0, stream>>>(ws_u, ws_g, chunkS);
        phaseA2<16><<<512, 256, 0, stream>>>(chunkS);
        phaseB<16, 64><<<512, 256, 0, stream>>>(ws_u, ws_g, chunkS, W,
                                                out_grads, out_next);
    }
    lossk<<<1, 256, 0, stream>>>(lossbuf, out_loss);
}

// Round 5
// 615.233 us; speedup vs baseline: 1.0215x; 1.0156x over previous
//
#include <hip/hip_runtime.h>
#include <math.h>

#define D 128
#define NS 2048          // b*n = 2*1024

typedef float v4f __attribute__((ext_vector_type(4)));

__device__ __forceinline__ float sigmoidf_(float x) {
    return 1.0f / (1.0f + expf(-x));
}

// acc[s] = sum_r xsg[s][r] * M[r*D + lt]   (SB samples share each W load)
template<int SB>
__device__ __forceinline__ void matvecN(const float* __restrict__ M,
                                        const float (*xsg)[D], int lt,
                                        float acc[SB])
{
#pragma unroll
    for (int s = 0; s < SB; ++s) acc[s] = 0.f;
#pragma unroll 2
    for (int r = 0; r < D; r += 4) {
        v4f xv[SB];
#pragma unroll
        for (int s = 0; s < SB; ++s) xv[s] = *(const v4f*)&xsg[s][r];
#pragma unroll
        for (int rr = 0; rr < 4; ++rr) {
            float w = M[(r + rr) * D + lt];
#pragma unroll
            for (int s = 0; s < SB; ++s) acc[s] += xv[s][rr] * w;
        }
    }
}

// ---------------- Phase 0: transpose W so backward reads are coalesced ----
__global__ __launch_bounds__(256) void transposeW(
    const float* __restrict__ W, float* __restrict__ WT)
{
    const int l   = blockIdx.x >> 4;
    const int tl  = blockIdx.x & 15;
    const int tr  = tl >> 2, tc = tl & 3;
    const int tid = threadIdx.x;
    const int lr  = tid >> 5;      // 0..7
    const int lc  = tid & 31;
    __shared__ float tile[32][33];
#pragma unroll
    for (int k = 0; k < 4; ++k)
        tile[lr + 8 * k][lc] =
            W[l * 16384 + (tr * 32 + lr + 8 * k) * 128 + tc * 32 + lc];
    __syncthreads();
#pragma unroll
    for (int k = 0; k < 4; ++k)
        WT[l * 16384 + (tc * 32 + lr + 8 * k) * 128 + tr * 32 + lc] =
            tile[lc][lr + 8 * k];
}

// ---------------- Phase 1: forward/backward, 2*SB samples per block -------
// 256 threads = 2 groups x 128; each group processes SB samples sharing W loads.
// SB=2: 512 blocks, 8 waves/CU (2x the occupancy of SB=4 at 2x fewer loads
// than SB=1).
template<int SB>
__global__ __launch_bounds__(256) void phase1(
    const float* __restrict__ seq, const float* __restrict__ W,
    const float* __restrict__ WT, const float* __restrict__ Wkv,
    const float* __restrict__ w_lr,
    float* __restrict__ ws_u, float* __restrict__ ws_g,
    float* __restrict__ lossbuf)
{
    const int tid = threadIdx.x;
    const int g   = tid >> 7;        // sample-group 0/1
    const int lt  = tid & 127;       // lane within group = output dim
    const int wv  = lt >> 6;         // wave-half within group
    const int sbase = blockIdx.x * (2 * SB) + g * SB;

    __shared__ float sseq[2][SB][D];
    __shared__ float xs[2][SB][D];   // activations / gradient broadcast
    __shared__ float red[2][SB][2];

#pragma unroll
    for (int s = 0; s < SB; ++s)
        sseq[g][s][lt] = seq[(sbase + s) * D + lt];

    const float wlr = w_lr[lt];
#pragma unroll
    for (int s = 0; s < SB; ++s) {
        float p = sseq[g][s][lt] * wlr;
#pragma unroll
        for (int off = 32; off > 0; off >>= 1) p += __shfl_down(p, off, 64);
        if ((tid & 63) == 0) red[g][s][wv] = p;
    }
    __syncthreads();
    float sc[SB];
#pragma unroll
    for (int s = 0; s < SB; ++s) sc[s] = -(red[g][s][0] + red[g][s][1]);

    // kv = seq @ Wkv (k and v columns; W elements shared across SB samples)
    float ka[SB], va[SB];
#pragma unroll
    for (int s = 0; s < SB; ++s) { ka[s] = 0.f; va[s] = 0.f; }
#pragma unroll 2
    for (int r = 0; r < D; r += 4) {
        v4f xv[SB];
#pragma unroll
        for (int s = 0; s < SB; ++s) xv[s] = *(const v4f*)&sseq[g][s][r];
#pragma unroll
        for (int rr = 0; rr < 4; ++rr) {
            float wk  = Wkv[(r + rr) * 256 + lt];
            float wv2 = Wkv[(r + rr) * 256 + 128 + lt];
#pragma unroll
            for (int s = 0; s < SB; ++s) {
                ka[s] += xv[s][rr] * wk;
                va[s] += xv[s][rr] * wv2;
            }
        }
    }
    float vr[SB];
#pragma unroll
    for (int s = 0; s < SB; ++s) {
        vr[s] = va[s];
        xs[g][s][lt] = ka[s];
        ws_u[((size_t)(sbase + s) * 4 + 0) * D + lt] = ka[s];
    }
    __syncthreads();

    float h0r[SB], h1r[SB], h2r[SB], acc[SB];

    // layer 0
    matvecN<SB>(W + 0 * 16384, xs[g], lt, acc);
    __syncthreads();
#pragma unroll
    for (int s = 0; s < SB; ++s) {
        h0r[s] = acc[s];
        float a = acc[s] * sigmoidf_(acc[s]);
        xs[g][s][lt] = a;
        ws_u[((size_t)(sbase + s) * 4 + 1) * D + lt] = a;
    }
    __syncthreads();

    // layer 1
    matvecN<SB>(W + 1 * 16384, xs[g], lt, acc);
    __syncthreads();
#pragma unroll
    for (int s = 0; s < SB; ++s) {
        h1r[s] = acc[s];
        float a = acc[s] * sigmoidf_(acc[s]);
        xs[g][s][lt] = a;
        ws_u[((size_t)(sbase + s) * 4 + 2) * D + lt] = a;
    }
    __syncthreads();

    // layer 2
    matvecN<SB>(W + 2 * 16384, xs[g], lt, acc);
    __syncthreads();
#pragma unroll
    for (int s = 0; s < SB; ++s) {
        h2r[s] = acc[s];
        float a = acc[s] * sigmoidf_(acc[s]);
        xs[g][s][lt] = a;
        ws_u[((size_t)(sbase + s) * 4 + 3) * D + lt] = a;
    }
    __syncthreads();

    // layer 3 (no activation) -> pred
    matvecN<SB>(W + 3 * 16384, xs[g], lt, acc);
    float diff[SB];
#pragma unroll
    for (int s = 0; s < SB; ++s) diff[s] = acc[s] - vr[s];

    // loss
#pragma unroll
    for (int s = 0; s < SB; ++s) {
        float lp = diff[s] * diff[s];
#pragma unroll
        for (int off = 32; off > 0; off >>= 1) lp += __shfl_down(lp, off, 64);
        if ((tid & 63) == 0) red[g][s][wv] = lp;
    }
    __syncthreads();       // red visible; layer-3 xs reads complete
    if (lt == 0) {
#pragma unroll
        for (int s = 0; s < SB; ++s)
            lossbuf[sbase + s] = (red[g][s][0] + red[g][s][1]) * (1.0f / 128.0f);
    }

    // backward
    float gcur[SB];
#pragma unroll
    for (int s = 0; s < SB; ++s) {
        gcur[s] = diff[s] * (2.0f / 128.0f);
        xs[g][s][lt] = gcur[s];
        ws_g[((size_t)(sbase + s) * 4 + 3) * D + lt] = sc[s] * gcur[s];
    }
    __syncthreads();

    // da2 via WT3 ; g2 via h2
    matvecN<SB>(WT + 3 * 16384, xs[g], lt, acc);
    __syncthreads();       // xs reads complete before overwrite
#pragma unroll
    for (int s = 0; s < SB; ++s) {
        float hv = h2r[s], sg = sigmoidf_(hv);
        gcur[s] = acc[s] * (sg * (1.0f + hv * (1.0f - sg)));
        xs[g][s][lt] = gcur[s];
        ws_g[((size_t)(sbase + s) * 4 + 2) * D + lt] = sc[s] * gcur[s];
    }
    __syncthreads();

    // da1 via WT2 ; g1 via h1
    matvecN<SB>(WT + 2 * 16384, xs[g], lt, acc);
    __syncthreads();
#pragma unroll
    for (int s = 0; s < SB; ++s) {
        float hv = h1r[s], sg = sigmoidf_(hv);
        gcur[s] = acc[s] * (sg * (1.0f + hv * (1.0f - sg)));
        xs[g][s][lt] = gcur[s];
        ws_g[((size_t)(sbase + s) * 4 + 1) * D + lt] = sc[s] * gcur[s];
    }
    __syncthreads();

    // da0 via WT1 ; g0 via h0
    matvecN<SB>(WT + 1 * 16384, xs[g], lt, acc);
#pragma unroll
    for (int s = 0; s < SB; ++s) {
        float hv = h0r[s], sg = sigmoidf_(hv);
        gcur[s] = acc[s] * (sg * (1.0f + hv * (1.0f - sg)));
        ws_g[((size_t)(sbase + s) * 4 + 0) * D + lt] = sc[s] * gcur[s];
    }
}

// ---------------- Phase A: chunk sums (sum of CL rank-1 products) ---------
// block = (b, layer, chunk, row-half); 16*NCH blocks, 256 threads, 32 acc each.
template<int NCH, int CL>
__global__ __launch_bounds__(256) void phaseA(
    const float* __restrict__ ws_u, const float* __restrict__ ws_g,
    float* __restrict__ chunkS)
{
    const int bx    = blockIdx.x;
    const int half  = bx & 1;
    const int cs    = bx >> 1;            // 0..8*NCH-1
    const int j     = cs & (NCH - 1);
    const int layer = (cs / NCH) & 3;
    const int b     = cs / (NCH * 4);
    const int tid   = threadIdx.x;
    const int hi    = tid >> 7;           // 0/1
    const int c     = tid & 127;

    __shared__ float us[2][64], gs[2][D];
    float acc[32];
#pragma unroll
    for (int k = 0; k < 32; ++k) acc[k] = 0.f;

    const int samp0 = b * 1024 + j * CL;
    float ru = 0.f, rg = 0.f;
    if (tid < 128) rg = ws_g[(samp0 * 4 + layer) * D + tid];
    if (tid < 64)  ru = ws_u[(samp0 * 4 + layer) * D + half * 64 + tid];

    for (int t = 0; t < CL; ++t) {
        const int pb = t & 1;
        if (tid < 128) gs[pb][tid] = rg;
        if (tid < 64)  us[pb][tid] = ru;
        if (t + 1 < CL) {
            const int samp = samp0 + t + 1;
            if (tid < 128) rg = ws_g[(samp * 4 + layer) * D + tid];
            if (tid < 64)  ru = ws_u[(samp * 4 + layer) * D + half * 64 + tid];
        }
        __syncthreads();
        const float gv = gs[pb][c];
#pragma unroll
        for (int k = 0; k < 32; ++k) acc[k] += us[pb][2 * k + hi] * gv;
    }
    float* out = chunkS + (size_t)cs * 16384 + half * 8192;
#pragma unroll
    for (int k = 0; k < 32; ++k) out[k * 256 + tid] = acc[k];
}

// ---------------- Phase A2: exclusive scan of chunk sums + loss reduce ----
template<int NCH>
__global__ __launch_bounds__(256) void phaseA2(float* __restrict__ chunkS,
                                               const float* __restrict__ lossbuf,
                                               float* __restrict__ out_loss)
{
    const int g  = blockIdx.x * 256 + threadIdx.x;  // 0..131071
    const int bl = g >> 14;                         // (b,layer) 0..7
    const int e  = g & 16383;
    float* base = chunkS + (size_t)bl * NCH * 16384 + e;
    float run = 0.f;
    for (int j = 0; j < NCH; ++j) {
        float t = base[(size_t)j * 16384];
        base[(size_t)j * 16384] = run;
        run += t;
    }

    // fold the loss reduction into block 0 (saves a kernel launch)
    if (blockIdx.x == 0) {
        __shared__ float red[256];
        const int tid = threadIdx.x;
        float s = 0.f;
        for (int i = tid; i < NS; i += 256) s += lossbuf[i];
        red[tid] = s;
        __syncthreads();
        for (int off = 128; off > 0; off >>= 1) {
            if (tid < off) red[tid] += red[tid + off];
            __syncthreads();
        }
        if (tid == 0) out_loss[0] = red[0] * (1.0f / (float)NS);
    }
}

// ---------------- Phase B: carry + rank-1 scan, stream grads --------------
// 32*NCH blocks; 256 threads; tile 32 rows x 128 cols; NT stores.
template<int NCH, int CL>
__global__ __launch_bounds__(256) void phaseB(
    const float* __restrict__ ws_u, const float* __restrict__ ws_g,
    const float* __restrict__ chunkS, const float* __restrict__ W,
    float* __restrict__ out_grads, float* __restrict__ out_next)
{
    const int id    = blockIdx.x;
    const int rt    = id & 3;
    const int rest  = id >> 2;
    const int j     = rest & (NCH - 1);
    const int rest2 = rest / NCH;
    const int layer = rest2 & 3;
    const int b     = rest2 >> 2;
    const int cs    = (b * 4 + layer) * NCH + j;
    const int tid   = threadIdx.x;

    const int c4 = (tid & 31) * 4;        // column (x4)
    const int rq = tid >> 5;              // 0..7
    const int r0 = rt * 32 + rq * 4;      // 4 consecutive rows

    v4f acc[4];
    const float* carry = chunkS + (size_t)cs * 16384;
#pragma unroll
    for (int k = 0; k < 4; ++k)
        acc[k] = *(const v4f*)(carry + (r0 + k) * 128 + c4);

    const int samp0 = b * 1024 + j * CL;
    const float* gbase = ws_g + ((size_t)samp0 * 4 + layer) * D;
    const float* ubase = ws_u + ((size_t)samp0 * 4 + layer) * D;

    v4f gv = *(const v4f*)(gbase + c4);
    v4f u4 = *(const v4f*)(ubase + r0);

    for (int t = 0; t < CL; ++t) {
        v4f gn = gv, un = u4;
        if (t + 1 < CL) {
            gn = *(const v4f*)(gbase + (t + 1) * 512 + c4);
            un = *(const v4f*)(ubase + (t + 1) * 512 + r0);
        }
        float* obase = out_grads + ((size_t)(samp0 + t) * 4 + layer) * 16384;

        acc[0] += u4[0] * gv;
        acc[1] += u4[1] * gv;
        acc[2] += u4[2] * gv;
        acc[3] += u4[3] * gv;

        __builtin_nontemporal_store(acc[0], (v4f*)(obase + (r0 + 0) * 128 + c4));
        __builtin_nontemporal_store(acc[1], (v4f*)(obase + (r0 + 1) * 128 + c4));
        __builtin_nontemporal_store(acc[2], (v4f*)(obase + (r0 + 2) * 128 + c4));
        __builtin_nontemporal_store(acc[3], (v4f*)(obase + (r0 + 3) * 128 + c4));

        gv = gn; u4 = un;
    }

    if (j == NCH - 1) {
#pragma unroll
        for (int k = 0; k < 4; ++k) {
            const int r = r0 + k;
            v4f w4 = *(const v4f*)(W + layer * 16384 + r * 128 + c4);
            v4f o = acc[k] + w4;
            *(v4f*)(out_next + ((size_t)(b * 4 + layer)) * 16384 + r * 128 + c4) = o;
        }
    }
}

extern "C" void kernel_launch(void* const* d_in, const int* in_sizes, int n_in,
                              void* d_out, int out_size, void* d_ws, size_t ws_size,
                              hipStream_t stream)
{
    const float* seq   = (const float*)d_in[0];
    const float* W     = (const float*)d_in[1];
    const float* Wkv   = (const float*)d_in[2];
    const float* w_lr  = (const float*)d_in[3];
    // w_mom (d_in[4]) and w_decay (d_in[5]) do not affect any output.

    float* out = (float*)d_out;
    float* ws  = (float*)d_ws;

    // NCHUNK=32 needs 2097152 + 8*32*16384 + 2048 floats = ~25.2 MB of ws.
    // Fall back to NCHUNK=16 (~16.8 MB, the previously-verified footprint)
    // if the workspace is smaller.
    const size_t need32 = ((size_t)2097152 + (size_t)8 * 32 * 16384 + 2048) * 4;
    const bool big = ws_size >= need32;
    const size_t chunkFloats = (size_t)8 * (big ? 32 : 16) * 16384;

    float* ws_u    = ws;                          // 1048576 floats
    float* ws_g    = ws + 1048576;                // 1048576 floats
    float* chunkS  = ws + 2097152;                // chunkFloats floats
    float* lossbuf = ws + 2097152 + chunkFloats;  // 2048 floats
    // WT aliases chunkS: WT is only read during phase1; chunkS is first
    // written by phaseA, which runs strictly after phase1 on the stream.
    float* WT      = chunkS;                      // 65536 floats (4 layers)

    float* out_grads = out;                       // 134217728 floats
    float* out_next  = out + 134217728;           // 131072 floats
    float* out_loss  = out + 134348800;           // 1 float

    transposeW<<<64, 256, 0, stream>>>(W, WT);
    phase1<2><<<NS / 4, 256, 0, stream>>>(seq, W, WT, Wkv, w_lr, ws_u, ws_g,
                                          lossbuf);
    if (big) {
        phaseA<32, 32><<<512, 256, 0, stream>>>(ws_u, ws_g, chunkS);
        phaseA2<32><<<512, 256, 0, stream>>>(chunkS, lossbuf, out_loss);
        phaseB<32, 32><<<1024, 256, 0, stream>>>(ws_u, ws_g, chunkS, W,
                                                 out_grads, out_next);
    } else {
        phaseA<16, 64><<<256, 256, 0, stream>>>(ws_u, ws_g, chunkS);
        phaseA2<16><<<512, 256, 0, stream>>>(chunkS, lossbuf, out_loss);
        phaseB<16, 64><<<512, 256, 0, stream>>>(ws_u, ws_g, chunkS, W,
                                                out_grads, out_next);
    }
}